// Round 8
// baseline (243.285 us; speedup 1.0000x reference)
//
#include <hip/hip_runtime.h>
#include <hip/hip_bf16.h>
#include <math.h>

typedef __attribute__((ext_vector_type(8))) short bf16x8;
typedef __attribute__((ext_vector_type(16))) float f32x16;

__device__ __forceinline__ float sigf(float x) { return 1.0f / (1.0f + expf(-x)); }

// prep: ta[row=b,i,j][c] = adj[b,i,j]*relu(edge@W1+b1) (bf16), h (f32), msk,
//       BT[n][v] = W2[n&127][(n>>7)*32+v]  (bf16).  grid = 2048 x 256.
__global__ __launch_bounds__(256, 4) void k_prep(
    const float* __restrict__ edge, const float* __restrict__ adj,
    const float* __restrict__ W1, const float* __restrict__ b1,
    const float* __restrict__ x, const float* __restrict__ W_emb,
    const float* __restrict__ b_emb, const float* __restrict__ W2,
    __hip_bfloat16* __restrict__ ta, __hip_bfloat16* __restrict__ BT,
    float* __restrict__ h, float* __restrict__ msk) {
    __shared__ float es[512];      // 32 rows x 16
    __shared__ float adjs2[32];
    __shared__ float xs[256];
    const int tid = threadIdx.x, bid = blockIdx.x;
    const int c = tid & 127, g = tid >> 7;
    float wr[16];
    #pragma unroll
    for (int v = 0; v < 16; ++v) wr[v] = W1[v * 128 + c];
    const float b1c = b1[c];
    if (tid < 128) ((float4*)es)[tid] = ((const float4*)(edge + (long)bid * 512))[tid];
    if (tid >= 128 && tid < 160) adjs2[tid - 128] = adj[bid * 32 + (tid - 128)];
    if (bid < 256 && tid < 256) xs[tid] = x[bid * 256 + tid];
    __syncthreads();
    {   // edge MLP: rows g*16 .. g*16+15, col c
        const int r0 = g * 16;
        #pragma unroll
        for (int r = 0; r < 16; ++r) {
            const float* er = es + (r0 + r) * 16;
            float acc = b1c;
            #pragma unroll
            for (int k = 0; k < 16; ++k) acc += er[k] * wr[k];
            float av = adjs2[r0 + r];
            ta[((long)bid * 32 + r0 + r) * 128 + c] = __float2bfloat16(av * fmaxf(acc, 0.f));
        }
    }
    if (bid < 256) {            // embed: 8 rows of (b*N+n)
        int r = tid >> 5, u = tid & 31;
        int rowe = bid * 8 + r;
        float acc = b_emb[u];
        #pragma unroll
        for (int k = 0; k < 32; ++k) acc += xs[r * 32 + k] * W_emb[k * 32 + u];
        h[rowe * 32 + u] = acc;
        if (u == 0) {
            float s = 0.f;
            #pragma unroll
            for (int k = 0; k < 32; ++k) s += xs[r * 32 + k];
            msk[rowe] = (s > 0.f) ? 1.f : 0.f;
        }
    } else if (bid < 384) {     // BT
        int base = (bid - 256) * 1024;
        #pragma unroll
        for (int q = 0; q < 4; ++q) {
            int idx = base + q * 256 + tid;
            int n = idx >> 5, v = idx & 31;
            BT[idx] = __float2bfloat16(W2[(n & 127) * 1024 + (n >> 7) * 32 + v]);
        }
    }
}

// the whole network after prep: one block per b (64 x 1024), 3 layers + Set2Set.
__global__ __launch_bounds__(1024, 1) void k_net(
    const __hip_bfloat16* __restrict__ BT, const __hip_bfloat16* __restrict__ ta,
    const float* __restrict__ h0, const float* __restrict__ adj,
    const float* __restrict__ msk,
    const float* __restrict__ gWi, const float* __restrict__ gWh,
    const float* __restrict__ gbi, const float* __restrict__ gbh,
    const float* __restrict__ b2,
    const float* __restrict__ lWi, const float* __restrict__ lWh,
    const float* __restrict__ lbi, const float* __restrict__ lbh,
    const float* __restrict__ Wf, const float* __restrict__ bf,
    float* __restrict__ out) {
    __shared__ __align__(16) char Gbuf[65536];   // G chunk (8i x 8KB) / msg-reduce
    __shared__ float hsh[1024];
    __shared__ __align__(16) short hbfsh[1024];
    __shared__ float adjs[1024];
    __shared__ float wWiT[3104];   // [v*97 + k], k<96
    __shared__ float wWhT[3104];
    __shared__ float b2s[1056];    // [v*33 + u]
    __shared__ float gbs[192];
    __shared__ float hsumL[1024], mLs[1024];
    __shared__ float mskk[32], qs[32], cs2[32], qstar[64], gsv[128], asv[32];

    const int tid = threadIdx.x, b = blockIdx.x;
    const int w = tid >> 6, l64 = tid & 63, lid = l64 & 31, kh = l64 >> 5;
    const int j = tid >> 5, u = tid & 31;

    {   // stage (block = 1024 threads; everything strided or guarded < 1024)
        float hv = h0[b * 1024 + tid];
        hsh[tid] = hv;
        hbfsh[tid] = (short)__bfloat16_as_ushort(__float2bfloat16(hv));
        adjs[tid] = adj[b * 1024 + tid];
        if (tid < 32) mskk[tid] = msk[b * 32 + tid];
        for (int idx = tid; idx < 3072; idx += 1024)
            wWiT[(idx & 31) * 97 + (idx >> 5)] = gWi[idx];
        for (int idx = tid; idx < 3072; idx += 1024)
            wWhT[(idx & 31) * 97 + (idx >> 5)] = gWh[idx];
        if (tid < 96) gbs[tid] = gbi[tid];
        else if (tid < 192) gbs[tid] = gbh[tid - 96];
        b2s[(tid & 31) * 33 + (tid >> 5)] = b2[tid];
    }
    __syncthreads();

    for (int layer = 0; layer < 3; ++layer) {
        f32x16 acc = {};
        for (int ig = 0; ig < 4; ++ig) {
            // ---- G phase: all 16 waves, wave covers nt = w*8 .. w*8+7 ----
            {
                const short* ap = &hbfsh[(ig * 8 + (lid & 7)) * 32 + kh * 8];
                bf16x8 a0 = *(const bf16x8*)ap;
                bf16x8 a1 = *(const bf16x8*)(ap + 16);
                #pragma unroll
                for (int q = 0; q < 8; ++q) {
                    int nt = w * 8 + q;
                    const short* bp = (const short*)BT + (nt * 32 + lid) * 32 + kh * 8;
                    bf16x8 b0 = *(const bf16x8*)bp;
                    bf16x8 b1v = *(const bf16x8*)(bp + 16);
                    f32x16 accg = {};
                    accg = __builtin_amdgcn_mfma_f32_32x32x16_bf16(a0, b0, accg, 0, 0, 0);
                    accg = __builtin_amdgcn_mfma_f32_32x32x16_bf16(a1, b1v, accg, 0, 0, 0);
                    int n = nt * 32 + lid;
                    int uu = n >> 7, cc = n & 127;
                    int byteoff = (uu * 256 + cc * 2) ^ ((uu & 15) << 4);
                    #pragma unroll
                    for (int r = 0; r < 4; ++r)   // i-slot = r + 4*kh
                        *(__hip_bfloat16*)(Gbuf + (r + 4 * kh) * 8192 + byteoff) =
                            __float2bfloat16(accg[r]);
                }
            }
            __syncthreads();
            // ---- msg phase: waves 0..7, i-slot = w, acc carried across ig ----
            if (w < 8) {
                long bi = b * 32 + ig * 8 + w;
                const short* tp = (const short*)ta + (bi * 32 + lid) * 128 + kh * 8;
                char* gs = Gbuf + w * 8192;
                #pragma unroll
                for (int kk = 0; kk < 8; ++kk) {
                    bf16x8 af = *(const bf16x8*)(tp + kk * 16);
                    int byteoff = (lid * 256 + kh * 16 + kk * 32) ^ ((lid & 15) << 4);
                    bf16x8 bfr = *(const bf16x8*)(gs + byteoff);
                    acc = __builtin_amdgcn_mfma_f32_32x32x16_bf16(af, bfr, acc, 0, 0, 0);
                }
            }
            __syncthreads();
        }
        // ---- partial dump (reuse Gbuf as red[8][1024] f32) ----
        if (w < 8) {
            float* red = (float*)Gbuf + w * 1024;
            #pragma unroll
            for (int r = 0; r < 16; ++r) {
                int crow = (r & 3) + 8 * (r >> 2) + 4 * kh;
                red[crow * 32 + lid] = acc[r];
            }
        }
        __syncthreads();
        // ---- reduce + b2 + GRU (1024 threads = 32j x 32u) ----
        {
            float ps = 0.f;
            #pragma unroll
            for (int w8 = 0; w8 < 8; ++w8) ps += ((float*)Gbuf)[w8 * 1024 + tid];
            float hs = 0.f;
            #pragma unroll
            for (int i = 0; i < 32; ++i) hs += adjs[i * 32 + j] * hsh[i * 32 + u];
            hsumL[tid] = hs;
            __syncthreads();
            float m = ps;
            #pragma unroll
            for (int v = 0; v < 32; ++v) m += b2s[v * 33 + u] * hsumL[j * 32 + v];
            mLs[tid] = m;
            __syncthreads();
            float gi[3], gh[3];
            #pragma unroll
            for (int kb = 0; kb < 3; ++kb) {
                int k = kb * 32 + u;
                float a = gbs[k], c = gbs[96 + k];
                #pragma unroll
                for (int v = 0; v < 32; ++v) {
                    a += mLs[j * 32 + v] * wWiT[v * 97 + k];
                    c += hsh[j * 32 + v] * wWhT[v * 97 + k];
                }
                gi[kb] = a; gh[kb] = c;
            }
            float r = sigf(gi[0] + gh[0]);
            float z = sigf(gi[1] + gh[1]);
            float n = tanhf(gi[2] + r * gh[2]);
            float hv = hsh[tid];
            float mm = mskk[j];
            float res = mm * ((1.f - z) * n + z * hv);
            hsh[tid] = res;                      // in-order within wave: reads precede write
            hbfsh[tid] = (short)__bfloat16_as_ushort(__float2bfloat16(res));
        }
        __syncthreads();
    }

    // ================= Set2Set + final fc =================
    if (tid < 64) { qstar[tid] = 0.f; if (tid < 32) { qs[tid] = 0.f; cs2[tid] = 0.f; } }
    __syncthreads();
    for (int step = 0; step < 3; ++step) {
        if (tid < 128) {
            float g = lbi[tid] + lbh[tid];
            #pragma unroll
            for (int pp = 0; pp < 64; ++pp) g += qstar[pp] * lWi[tid * 64 + pp];
            #pragma unroll
            for (int v = 0; v < 32; ++v) g += qs[v] * lWh[tid * 32 + v];
            gsv[tid] = g;
        }
        __syncthreads();
        if (tid < 32) {
            float ci = sigf(gsv[32 + tid]) * cs2[tid] + sigf(gsv[tid]) * tanhf(gsv[64 + tid]);
            cs2[tid] = ci;
            qs[tid] = sigf(gsv[96 + tid]) * tanhf(ci);
        }
        __syncthreads();
        if (tid < 32) {
            float e = 0.f;
            #pragma unroll
            for (int v = 0; v < 32; ++v) e += hsh[tid * 32 + v] * qs[v];
            e = (mskk[tid] == 0.f) ? -INFINITY : e;
            float mx = e;
            for (int o = 16; o >= 1; o >>= 1) mx = fmaxf(mx, __shfl_xor(mx, o, 64));
            float a = expf(e - mx);
            float ss = a;
            for (int o = 16; o >= 1; o >>= 1) ss += __shfl_xor(ss, o, 64);
            asv[tid] = a / ss;
        }
        __syncthreads();
        if (tid < 32) {
            float rr = 0.f;
            #pragma unroll
            for (int nn = 0; nn < 32; ++nn) rr += asv[nn] * hsh[nn * 32 + tid] * mskk[nn];
            qstar[tid] = qs[tid];
            qstar[32 + tid] = rr;
        }
        __syncthreads();
    }
    if (tid < 64) {
        float v = qstar[tid] * Wf[tid];
        for (int o = 32; o >= 1; o >>= 1) v += __shfl_xor(v, o, 64);
        if (tid == 0) out[b] = v + bf[0];
    }
}

extern "C" void kernel_launch(void* const* d_in, const int* in_sizes, int n_in,
                              void* d_out, int out_size, void* d_ws, size_t ws_size,
                              hipStream_t stream) {
    const float* x    = (const float*)d_in[0];
    const float* edge = (const float*)d_in[1];
    const float* adj  = (const float*)d_in[2];
    const float* W_emb= (const float*)d_in[3];
    const float* b_emb= (const float*)d_in[4];
    const float* W1   = (const float*)d_in[5];
    const float* b1   = (const float*)d_in[6];
    const float* W2   = (const float*)d_in[7];
    const float* b2   = (const float*)d_in[8];
    const float* gWi  = (const float*)d_in[9];
    const float* gWh  = (const float*)d_in[10];
    const float* gbi  = (const float*)d_in[11];
    const float* gbh  = (const float*)d_in[12];
    const float* lWi  = (const float*)d_in[13];
    const float* lWh  = (const float*)d_in[14];
    const float* lbi  = (const float*)d_in[15];
    const float* lbh  = (const float*)d_in[16];
    const float* Wf   = (const float*)d_in[17];
    const float* bf   = (const float*)d_in[18];
    float* out = (float*)d_out;

    __hip_bfloat16* ta = (__hip_bfloat16*)d_ws;         // 8388608 bf16
    __hip_bfloat16* BT = ta + 8388608;                  // 131072 bf16
    float* hA   = (float*)(BT + 131072);                // 65536 f32
    float* mskp = hA + 65536;                           // 2048 f32

    k_prep<<<2048, 256, 0, stream>>>(edge, adj, W1, b1, x, W_emb, b_emb, W2,
                                     ta, BT, hA, mskp);
    k_net<<<64, 1024, 0, stream>>>(BT, ta, hA, adj, mskp,
                                   gWi, gWh, gbi, gbh, b2,
                                   lWi, lWh, lbi, lbh, Wf, bf, out);
}

// Round 10
// 198.068 us; speedup vs baseline: 1.2283x; 1.2283x over previous
//
#include <hip/hip_runtime.h>
#include <hip/hip_bf16.h>
#include <math.h>

typedef __attribute__((ext_vector_type(8))) short bf16x8;
typedef __attribute__((ext_vector_type(16))) float f32x16;

__device__ __forceinline__ float sigf(float x) { return 1.0f / (1.0f + expf(-x)); }

// prep: taT2[b][j][c][i] = adj[b,i,j]*relu(edge@W1+b1) (bf16, i contiguous),
//       h (f32), msk, W2FTB[cv>>4][u][cv&15] = W2[cv>>5][u*32+(cv&31)] (bf16 blocked).
// grid = 2048 (b = bid>>5, j = bid&31) x 256 thr.
__global__ __launch_bounds__(256, 4) void k_prep(
    const float* __restrict__ edge, const float* __restrict__ adj,
    const float* __restrict__ W1, const float* __restrict__ b1,
    const float* __restrict__ x, const float* __restrict__ W_emb,
    const float* __restrict__ b_emb, const float* __restrict__ W2,
    __hip_bfloat16* __restrict__ taT2, __hip_bfloat16* __restrict__ W2FTB,
    float* __restrict__ h, float* __restrict__ msk) {
    __shared__ float es[512];       // [i][k] 32x16
    __shared__ float adjv[32];
    __shared__ float xs[256];
    __shared__ short t_lds[4096];   // [c][i]
    const int tid = threadIdx.x, bid = blockIdx.x;
    const int b = bid >> 5, j = bid & 31;
    const int c = tid & 127, g = tid >> 7;
    float wr[16];
    #pragma unroll
    for (int v = 0; v < 16; ++v) wr[v] = W1[v * 128 + c];
    const float b1c = b1[c];
    if (tid < 128) {
        int i = tid >> 2, k4 = tid & 3;
        ((float4*)es)[tid] = *(const float4*)&edge[(((long)(b * 32 + i)) * 32 + j) * 16 + k4 * 4];
    } else if (tid < 160) {
        int i = tid - 128;
        adjv[i] = adj[(b * 32 + i) * 32 + j];
    }
    if (bid < 256) xs[tid] = x[bid * 256 + tid];
    __syncthreads();
    {   // edge MLP for i = g*16 .. +15, col c -> t_lds[c][i]
        #pragma unroll
        for (int ii = 0; ii < 16; ++ii) {
            int i = g * 16 + ii;
            const float* er = es + i * 16;
            float acc = b1c;
            #pragma unroll
            for (int k = 0; k < 16; ++k) acc += er[k] * wr[k];
            float val = adjv[i] * fmaxf(acc, 0.f);
            t_lds[c * 32 + i] = (short)__bfloat16_as_ushort(__float2bfloat16(val));
        }
    }
    __syncthreads();
    {   // coalesced copy out: 4096 bf16 = 512 int4
        int4* dst = (int4*)(taT2 + (long)bid * 4096);
        const int4* src = (const int4*)t_lds;
        dst[tid] = src[tid];
        dst[tid + 256] = src[tid + 256];
    }
    if (bid < 256) {            // embed: 8 rows of (b*N+n)
        int r = tid >> 5, u = tid & 31;
        int rowe = bid * 8 + r;
        float acc = b_emb[u];
        #pragma unroll
        for (int k = 0; k < 32; ++k) acc += xs[r * 32 + k] * W_emb[k * 32 + u];
        h[rowe * 32 + u] = acc;
        if (u == 0) {
            float s = 0.f;
            #pragma unroll
            for (int k = 0; k < 32; ++k) s += xs[r * 32 + k];
            msk[rowe] = (s > 0.f) ? 1.f : 0.f;
        }
    } else if (bid < 384) {     // W2FTB: 128 blocks x 1024 elements
        int base = (bid - 256) * 1024;
        #pragma unroll
        for (int q = 0; q < 4; ++q) {
            int idx = base + q * 256 + tid;
            int chunk = idx >> 9, u = (idx >> 4) & 31, inner = idx & 15;
            int cv = chunk * 16 + inner;
            int cc = cv >> 5, v = cv & 31;
            W2FTB[idx] = __float2bfloat16(W2[cc * 1024 + u * 32 + v]);
        }
    }
}

// whole network after prep: one block per b (64 x 1024), 3 layers + Set2Set.
// Per layer, 4 c-chunks of 32: GEMM1 P_chunk[j][clocal][v] (64KB LDS, exact fit),
// GEMM2 m += P_chunk @ W2FTB-slice (acc across chunks), then red -> GRU.
__global__ __launch_bounds__(1024, 1) void k_net(
    const __hip_bfloat16* __restrict__ taT2, const __hip_bfloat16* __restrict__ W2FTB,
    const float* __restrict__ h0, const float* __restrict__ adj,
    const float* __restrict__ msk,
    const float* __restrict__ gWi, const float* __restrict__ gWh,
    const float* __restrict__ gbi, const float* __restrict__ gbh,
    const float* __restrict__ b2,
    const float* __restrict__ lWi, const float* __restrict__ lWh,
    const float* __restrict__ lbi, const float* __restrict__ lbh,
    const float* __restrict__ Wf, const float* __restrict__ bf,
    float* __restrict__ out) {
    __shared__ __align__(16) char P_lds[65536];   // P chunk (bf16 blocked) / red (16x4KB f32)
    __shared__ float hsh[1024];
    __shared__ __align__(16) short hT[1024];      // [v][i]
    __shared__ float adjs[1024];
    __shared__ float wWiT[3104];   // [v*97 + k]
    __shared__ float wWhT[3104];
    __shared__ float b2s[1056];    // [v*33 + u]
    __shared__ float gbs[192];
    __shared__ float hsumL[1024], mLs[1024];
    __shared__ float mskk[32], qs[32], cs2[32], qstar[64], gsv[128], asv[32];

    const int tid = threadIdx.x, b = blockIdx.x;
    const int w = tid >> 6, l64 = tid & 63, lid = l64 & 31, kh = l64 >> 5;
    const int j = tid >> 5, u = tid & 31;

    {   // stage
        float hv = h0[b * 1024 + tid];
        hsh[tid] = hv;
        adjs[tid] = adj[b * 1024 + tid];
        if (tid < 32) mskk[tid] = msk[b * 32 + tid];
        for (int idx = tid; idx < 3072; idx += 1024)
            wWiT[(idx & 31) * 97 + (idx >> 5)] = gWi[idx];
        for (int idx = tid; idx < 3072; idx += 1024)
            wWhT[(idx & 31) * 97 + (idx >> 5)] = gWh[idx];
        if (tid < 96) gbs[tid] = gbi[tid];
        else if (tid < 192) gbs[tid] = gbh[tid - 96];
        b2s[(tid & 31) * 33 + (tid >> 5)] = b2[tid];
    }
    __syncthreads();

    const short* taB = (const short*)taT2 + (long)b * 131072;
    const short* w2b = (const short*)W2FTB;

    for (int layer = 0; layer < 3; ++layer) {
        // ---- build hT[v][i] (bf16) from hsh ----
        hT[(tid & 31) * 32 + (tid >> 5)] =
            (short)__bfloat16_as_ushort(__float2bfloat16(hsh[tid]));
        __syncthreads();
        f32x16 acc = {};
        const short* hTp = hT + lid * 32 + kh * 8;
        bf16x8 hb0 = *(const bf16x8*)hTp;          // B: col=v=lid, k=i=kh*8+e
        bf16x8 hb1 = *(const bf16x8*)(hTp + 16);   // k=i=16+kh*8+e
        for (int cq = 0; cq < 4; ++cq) {
            // ---- GEMM1: wave w computes j = 2w, 2w+1; c = cq*32 + crow ----
            #pragma unroll
            for (int q = 0; q < 2; ++q) {
                int jj = w * 2 + q;
                const short* ap = taB + (jj * 128 + cq * 32 + lid) * 32 + kh * 8;
                bf16x8 a0 = *(const bf16x8*)ap;
                bf16x8 a1 = *(const bf16x8*)(ap + 16);
                f32x16 accg = {};
                accg = __builtin_amdgcn_mfma_f32_32x32x16_bf16(a0, hb0, accg, 0, 0, 0);
                accg = __builtin_amdgcn_mfma_f32_32x32x16_bf16(a1, hb1, accg, 0, 0, 0);
                #pragma unroll
                for (int r = 0; r < 16; ++r) {
                    int crow = (r & 3) + 8 * (r >> 2) + 4 * kh;   // = clocal
                    // cv_l = crow*32+lid -> [chunk16][khidx][j][e]
                    int byte = (crow * 2 + (lid >> 4)) * 1024 + ((lid >> 3) & 1) * 512
                             + jj * 16 + (lid & 7) * 2;
                    *(short*)(P_lds + byte) =
                        (short)__bfloat16_as_ushort(__float2bfloat16(accg[r]));
                }
            }
            __syncthreads();
            // ---- GEMM2: wave w covers local cv in [w*64, w*64+64) ----
            #pragma unroll
            for (int kk = 0; kk < 4; ++kk) {
                int k0 = w * 64 + kk * 16;
                bf16x8 a = *(const bf16x8*)(P_lds + (k0 >> 4) * 1024 + kh * 512 + lid * 16);
                bf16x8 bg = *(const bf16x8*)(w2b + (cq * 64 + (k0 >> 4)) * 512 + lid * 16 + kh * 8);
                acc = __builtin_amdgcn_mfma_f32_32x32x16_bf16(a, bg, acc, 0, 0, 0);
            }
            __syncthreads();   // P reads done before next chunk overwrites
        }
        // ---- partial dump (reuse P_lds as red[16][1024] f32) ----
        {
            float* red = (float*)P_lds + w * 1024;
            #pragma unroll
            for (int r = 0; r < 16; ++r) {
                int crow = (r & 3) + 8 * (r >> 2) + 4 * kh;
                red[crow * 32 + lid] = acc[r];
            }
        }
        __syncthreads();
        // ---- reduce + b2 + GRU (1024 thr = 32j x 32u) ----
        {
            float ps = 0.f;
            #pragma unroll
            for (int w16 = 0; w16 < 16; ++w16) ps += ((float*)P_lds)[w16 * 1024 + tid];
            float hs = 0.f;
            #pragma unroll
            for (int i = 0; i < 32; ++i) hs += adjs[i * 32 + j] * hsh[i * 32 + u];
            hsumL[tid] = hs;
            __syncthreads();
            float m = ps;
            #pragma unroll
            for (int v = 0; v < 32; ++v) m += b2s[v * 33 + u] * hsumL[j * 32 + v];
            mLs[tid] = m;
            __syncthreads();
            float gi[3], gh[3];
            #pragma unroll
            for (int kb = 0; kb < 3; ++kb) {
                int k = kb * 32 + u;
                float a = gbs[k], cgh = gbs[96 + k];
                #pragma unroll
                for (int v = 0; v < 32; ++v) {
                    a   += mLs[j * 32 + v] * wWiT[v * 97 + k];
                    cgh += hsh[j * 32 + v] * wWhT[v * 97 + k];
                }
                gi[kb] = a; gh[kb] = cgh;
            }
            float r = sigf(gi[0] + gh[0]);
            float z = sigf(gi[1] + gh[1]);
            float n = tanhf(gi[2] + r * gh[2]);
            float hv = hsh[tid];
            float mm = mskk[j];
            float res = mm * ((1.f - z) * n + z * hv);
            hsh[tid] = res;   // wave-local rows; cross-wave reads were pre-barrier
        }
        __syncthreads();
    }

    // ================= Set2Set + final fc =================
    if (tid < 64) { qstar[tid] = 0.f; if (tid < 32) { qs[tid] = 0.f; cs2[tid] = 0.f; } }
    __syncthreads();
    for (int step = 0; step < 3; ++step) {
        if (tid < 128) {
            float g = lbi[tid] + lbh[tid];
            #pragma unroll
            for (int pp = 0; pp < 64; ++pp) g += qstar[pp] * lWi[tid * 64 + pp];
            #pragma unroll
            for (int v = 0; v < 32; ++v) g += qs[v] * lWh[tid * 32 + v];
            gsv[tid] = g;
        }
        __syncthreads();
        if (tid < 32) {
            float ci = sigf(gsv[32 + tid]) * cs2[tid] + sigf(gsv[tid]) * tanhf(gsv[64 + tid]);
            cs2[tid] = ci;
            qs[tid] = sigf(gsv[96 + tid]) * tanhf(ci);
        }
        __syncthreads();
        if (tid < 32) {
            float e = 0.f;
            #pragma unroll
            for (int v = 0; v < 32; ++v) e += hsh[tid * 32 + v] * qs[v];
            e = (mskk[tid] == 0.f) ? -INFINITY : e;
            float mx = e;
            for (int o = 16; o >= 1; o >>= 1) mx = fmaxf(mx, __shfl_xor(mx, o, 64));
            float a = expf(e - mx);
            float ss = a;
            for (int o = 16; o >= 1; o >>= 1) ss += __shfl_xor(ss, o, 64);
            asv[tid] = a / ss;
        }
        __syncthreads();
        if (tid < 32) {
            float rr = 0.f;
            #pragma unroll
            for (int nn = 0; nn < 32; ++nn) rr += asv[nn] * hsh[nn * 32 + tid] * mskk[nn];
            qstar[tid] = qs[tid];
            qstar[32 + tid] = rr;
        }
        __syncthreads();
    }
    if (tid < 64) {
        float v = qstar[tid] * Wf[tid];
        for (int o = 32; o >= 1; o >>= 1) v += __shfl_xor(v, o, 64);
        if (tid == 0) out[b] = v + bf[0];
    }
}

extern "C" void kernel_launch(void* const* d_in, const int* in_sizes, int n_in,
                              void* d_out, int out_size, void* d_ws, size_t ws_size,
                              hipStream_t stream) {
    const float* x    = (const float*)d_in[0];
    const float* edge = (const float*)d_in[1];
    const float* adj  = (const float*)d_in[2];
    const float* W_emb= (const float*)d_in[3];
    const float* b_emb= (const float*)d_in[4];
    const float* W1   = (const float*)d_in[5];
    const float* b1   = (const float*)d_in[6];
    const float* W2   = (const float*)d_in[7];
    const float* b2   = (const float*)d_in[8];
    const float* gWi  = (const float*)d_in[9];
    const float* gWh  = (const float*)d_in[10];
    const float* gbi  = (const float*)d_in[11];
    const float* gbh  = (const float*)d_in[12];
    const float* lWi  = (const float*)d_in[13];
    const float* lWh  = (const float*)d_in[14];
    const float* lbi  = (const float*)d_in[15];
    const float* lbh  = (const float*)d_in[16];
    const float* Wf   = (const float*)d_in[17];
    const float* bf   = (const float*)d_in[18];
    float* out = (float*)d_out;

    __hip_bfloat16* taT2  = (__hip_bfloat16*)d_ws;      // 64*32*128*32 = 8388608 bf16
    __hip_bfloat16* W2FTB = taT2 + 8388608;             // 131072 bf16
    float* hA   = (float*)(W2FTB + 131072);             // 65536 f32
    float* mskp = hA + 65536;                           // 2048 f32

    k_prep<<<2048, 256, 0, stream>>>(edge, adj, W1, b1, x, W_emb, b_emb, W2,
                                     taT2, W2FTB, hA, mskp);
    k_net<<<64, 1024, 0, stream>>>(taT2, W2FTB, hA, adj, mskp,
                                   gWi, gWh, gbi, gbh, b2,
                                   lWi, lWh, lbi, lbh, Wf, bf, out);
}

// Round 11
// 101.843 us; speedup vs baseline: 2.3888x; 1.9448x over previous
//
#include <hip/hip_runtime.h>
#include <hip/hip_bf16.h>
#include <math.h>

typedef __attribute__((ext_vector_type(8))) short bf16x8;
typedef __attribute__((ext_vector_type(16))) float f32x16;

__device__ __forceinline__ float sigf(float x) { return 1.0f / (1.0f + expf(-x)); }

// prep: taT2[b][j][c][i] = adj[b,i,j]*relu(edge@W1+b1) (bf16, i contiguous),
//       h (f32), msk, W2FTB[cv>>4][u][cv&15] = W2[cv>>5][u*32+(cv&31)] (bf16),
//       transposed small weights for k_gru/k_s2s.
// grid = 2048 (b = bid>>5, j = bid&31) x 256 thr.
__global__ __launch_bounds__(256, 4) void k_prep(
    const float* __restrict__ edge, const float* __restrict__ adj,
    const float* __restrict__ W1, const float* __restrict__ b1,
    const float* __restrict__ x, const float* __restrict__ W_emb,
    const float* __restrict__ b_emb, const float* __restrict__ W2,
    const float* __restrict__ gWi, const float* __restrict__ gWh,
    const float* __restrict__ b2, const float* __restrict__ lWi,
    const float* __restrict__ lWh,
    __hip_bfloat16* __restrict__ taT2, __hip_bfloat16* __restrict__ W2FTB,
    float* __restrict__ h, float* __restrict__ msk,
    float* __restrict__ gWiT, float* __restrict__ gWhT, float* __restrict__ b2T,
    float* __restrict__ lWiT, float* __restrict__ lWhT) {
    __shared__ float es[512];       // [i][k] 32x16
    __shared__ float adjv[32];
    __shared__ float xs[256];
    __shared__ short t_lds[4096];   // [c][i]
    const int tid = threadIdx.x, bid = blockIdx.x;
    const int b = bid >> 5, j = bid & 31;
    const int c = tid & 127, g = tid >> 7;
    float wr[16];
    #pragma unroll
    for (int v = 0; v < 16; ++v) wr[v] = W1[v * 128 + c];
    const float b1c = b1[c];
    if (tid < 128) {
        int i = tid >> 2, k4 = tid & 3;
        ((float4*)es)[tid] = *(const float4*)&edge[(((long)(b * 32 + i)) * 32 + j) * 16 + k4 * 4];
    } else if (tid < 160) {
        int i = tid - 128;
        adjv[i] = adj[(b * 32 + i) * 32 + j];
    }
    if (bid < 256) xs[tid] = x[bid * 256 + tid];
    __syncthreads();
    {   // edge MLP for i = g*16 .. +15, col c -> t_lds[c][i]
        #pragma unroll
        for (int ii = 0; ii < 16; ++ii) {
            int i = g * 16 + ii;
            const float* er = es + i * 16;
            float acc = b1c;
            #pragma unroll
            for (int k = 0; k < 16; ++k) acc += er[k] * wr[k];
            float val = adjv[i] * fmaxf(acc, 0.f);
            t_lds[c * 32 + i] = (short)__bfloat16_as_ushort(__float2bfloat16(val));
        }
    }
    __syncthreads();
    {   // coalesced copy out: 4096 bf16 = 512 int4
        int4* dst = (int4*)(taT2 + (long)bid * 4096);
        const int4* src = (const int4*)t_lds;
        dst[tid] = src[tid];
        dst[tid + 256] = src[tid + 256];
    }
    if (bid < 256) {            // embed: 8 rows of (b*N+n)
        int r = tid >> 5, u = tid & 31;
        int rowe = bid * 8 + r;
        float acc = b_emb[u];
        #pragma unroll
        for (int k = 0; k < 32; ++k) acc += xs[r * 32 + k] * W_emb[k * 32 + u];
        h[rowe * 32 + u] = acc;
        if (u == 0) {
            float s = 0.f;
            #pragma unroll
            for (int k = 0; k < 32; ++k) s += xs[r * 32 + k];
            msk[rowe] = (s > 0.f) ? 1.f : 0.f;
        }
    } else if (bid < 384) {     // W2FTB: 128 blocks x 1024 elements
        int base = (bid - 256) * 1024;
        #pragma unroll
        for (int q = 0; q < 4; ++q) {
            int idx = base + q * 256 + tid;
            int chunk = idx >> 9, u = (idx >> 4) & 31, inner = idx & 15;
            int cv = chunk * 16 + inner;
            int cc = cv >> 5, v = cv & 31;
            W2FTB[idx] = __float2bfloat16(W2[cc * 1024 + u * 32 + v]);
        }
    } else if (bid == 384) {    // transposed weights
        for (int idx = tid; idx < 3072; idx += 256) gWiT[(idx & 31) * 96 + (idx >> 5)] = gWi[idx];
        for (int idx = tid; idx < 3072; idx += 256) gWhT[(idx & 31) * 96 + (idx >> 5)] = gWh[idx];
        for (int idx = tid; idx < 1024; idx += 256) b2T[(idx & 31) * 32 + (idx >> 5)] = b2[idx];
        for (int idx = tid; idx < 8192; idx += 256) lWiT[(idx & 63) * 128 + (idx >> 6)] = lWi[idx];
        for (int idx = tid; idx < 4096; idx += 256) lWhT[(idx & 31) * 128 + (idx >> 5)] = lWh[idx];
    }
}

// msg: grid 256 = (b = bid>>2, cq = bid&3), 256 thr (4 waves).
// GEMM1: P_chunk[j][clocal][v] = taT2-slice @ hT  (64KB LDS, blocked layout)
// GEMM2: partial_m[j][u] = P_chunk @ W2FTB-slice  -> partial[b][cq][j*32+u]
__global__ __launch_bounds__(256, 2) void k_msg(
    const __hip_bfloat16* __restrict__ taT2, const __hip_bfloat16* __restrict__ W2FTB,
    const float* __restrict__ h, float* __restrict__ partial) {
    __shared__ __align__(16) char P_lds[65536];
    __shared__ __align__(16) short hT[1024];     // [v][i]
    const int tid = threadIdx.x, bid = blockIdx.x;
    const int b = bid >> 2, cq = bid & 3;
    const int w = tid >> 6, l = tid & 63, lid = l & 31, kh = l >> 5;
    for (int idx = tid; idx < 1024; idx += 256)
        hT[(idx & 31) * 32 + (idx >> 5)] =
            (short)__bfloat16_as_ushort(__float2bfloat16(h[b * 1024 + idx]));
    __syncthreads();
    const short* taB = (const short*)taT2 + (long)b * 131072;
    const short* w2b = (const short*)W2FTB;
    const short* hTp = hT + lid * 32 + kh * 8;
    bf16x8 hb0 = *(const bf16x8*)hTp;          // B: col=v=lid, k=i=kh*8+e
    bf16x8 hb1 = *(const bf16x8*)(hTp + 16);
    // ---- GEMM1: wave w computes j = w*8 .. w*8+7 ----
    #pragma unroll 2
    for (int q = 0; q < 8; ++q) {
        int jj = w * 8 + q;
        const short* ap = taB + (jj * 128 + cq * 32 + lid) * 32 + kh * 8;
        bf16x8 a0 = *(const bf16x8*)ap;
        bf16x8 a1 = *(const bf16x8*)(ap + 16);
        f32x16 accg = {};
        accg = __builtin_amdgcn_mfma_f32_32x32x16_bf16(a0, hb0, accg, 0, 0, 0);
        accg = __builtin_amdgcn_mfma_f32_32x32x16_bf16(a1, hb1, accg, 0, 0, 0);
        #pragma unroll
        for (int r = 0; r < 16; ++r) {
            int crow = (r & 3) + 8 * (r >> 2) + 4 * kh;   // clocal
            int byte = (crow * 2 + (lid >> 4)) * 1024 + ((lid >> 3) & 1) * 512
                     + jj * 16 + (lid & 7) * 2;
            *(short*)(P_lds + byte) =
                (short)__bfloat16_as_ushort(__float2bfloat16(accg[r]));
        }
    }
    __syncthreads();
    // ---- GEMM2: wave w covers slices w*16 .. +15 (local cv = slice*16 + kh*8 + e) ----
    f32x16 acc = {};
    #pragma unroll
    for (int kk = 0; kk < 16; ++kk) {
        int slice = w * 16 + kk;
        bf16x8 a = *(const bf16x8*)(P_lds + slice * 1024 + kh * 512 + lid * 16);
        bf16x8 bg = *(const bf16x8*)(w2b + (cq * 64 + slice) * 512 + lid * 16 + kh * 8);
        acc = __builtin_amdgcn_mfma_f32_32x32x16_bf16(a, bg, acc, 0, 0, 0);
    }
    __syncthreads();   // P reads done before red overwrites
    {
        float* red = (float*)P_lds + w * 1024;
        #pragma unroll
        for (int r = 0; r < 16; ++r) {
            int crow = (r & 3) + 8 * (r >> 2) + 4 * kh;   // = j
            red[crow * 32 + lid] = acc[r];
        }
    }
    __syncthreads();
    {
        float* r0 = (float*)P_lds;
        for (int k = tid; k < 1024; k += 256)
            partial[(long)bid * 1024 + k] = r0[k] + r0[1024 + k] + r0[2048 + k] + r0[3072 + k];
    }
}

// GRU: 256 blocks (b = bid>>2, jc = bid&3) x 256 threads; LDS-staged, conflict-free.
__global__ __launch_bounds__(256, 2) void k_gru(
    const float* __restrict__ partial, const float* __restrict__ h,
    const float* __restrict__ adj, const float* __restrict__ msk,
    const float* __restrict__ b2T, const float* __restrict__ gWiT,
    const float* __restrict__ gWhT, const float* __restrict__ gbi,
    const float* __restrict__ gbh, float* __restrict__ hout) {
    __shared__ float hsh[1024], adjs[1024], wWiT[3072], wWhT[3072], b2s[1024];
    __shared__ float hsumL[256], mLs[256], gbs[192];
    const int tid = threadIdx.x, bid = blockIdx.x;
    const int b = bid >> 2, jc = bid & 3;
    const int j8 = tid >> 5, u = tid & 31, jg = jc * 8 + j8;
    for (int k = tid; k < 1024; k += 256) hsh[k] = h[b * 1024 + k];
    for (int k = tid; k < 1024; k += 256) adjs[k] = adj[b * 1024 + k];
    for (int k = tid; k < 3072; k += 256) wWiT[k] = gWiT[k];
    for (int k = tid; k < 3072; k += 256) wWhT[k] = gWhT[k];
    for (int k = tid; k < 1024; k += 256) b2s[k] = b2T[k];
    if (tid < 96) gbs[tid] = gbi[tid];
    else if (tid < 192) gbs[tid] = gbh[tid - 96];
    float ps = 0.f;
    #pragma unroll
    for (int cq = 0; cq < 4; ++cq)
        ps += partial[((long)(b * 4 + cq)) * 1024 + jc * 256 + tid];
    __syncthreads();
    float hs = 0.f;     // hsum[jg][u] = sum_i adj[b,i,jg]*h[b,i,u]
    #pragma unroll
    for (int i = 0; i < 32; ++i) hs += adjs[i * 32 + jg] * hsh[i * 32 + u];
    hsumL[tid] = hs;
    __syncthreads();
    float m = ps;
    #pragma unroll
    for (int v = 0; v < 32; ++v) m += b2s[v * 32 + u] * hsumL[j8 * 32 + v];
    mLs[tid] = m;
    __syncthreads();
    float gi[3], gh[3];
    #pragma unroll
    for (int kb = 0; kb < 3; ++kb) {
        int k = kb * 32 + u;
        float a = gbs[k], c = gbs[96 + k];
        #pragma unroll
        for (int v = 0; v < 32; ++v) {
            a += mLs[j8 * 32 + v] * wWiT[v * 96 + k];
            c += hsh[jg * 32 + v] * wWhT[v * 96 + k];
        }
        gi[kb] = a; gh[kb] = c;
    }
    float r = sigf(gi[0] + gh[0]);
    float z = sigf(gi[1] + gh[1]);
    float n = tanhf(gi[2] + r * gh[2]);
    float hv = hsh[jg * 32 + u];
    float mm = msk[b * 32 + jg];
    float res = mm * ((1.f - z) * n + z * hv);
    hout[b * 1024 + jg * 32 + u] = res;
}

// Set2Set + final fc. grid = B, block = 128.
__global__ __launch_bounds__(128, 4) void k_s2s(
    const float* __restrict__ h, const float* __restrict__ msk,
    const float* __restrict__ lWiT, const float* __restrict__ lWhT,
    const float* __restrict__ lbi, const float* __restrict__ lbh,
    const float* __restrict__ Wf, const float* __restrict__ bf,
    float* __restrict__ out) {
    __shared__ float hsh[1024];
    __shared__ float mskk[32], qs[32], cs2[32], qstar[64], gsv[128], asv[32];
    const int tid = threadIdx.x, b = blockIdx.x;
    for (int k = tid; k < 1024; k += 128) hsh[k] = h[b * 1024 + k];
    if (tid < 32) { mskk[tid] = msk[b * 32 + tid]; qs[tid] = 0.f; cs2[tid] = 0.f; }
    if (tid < 64) qstar[tid] = 0.f;
    __syncthreads();
    for (int step = 0; step < 3; ++step) {
        {
            float g = lbi[tid] + lbh[tid];
            #pragma unroll
            for (int pp = 0; pp < 64; ++pp) g += qstar[pp] * lWiT[pp * 128 + tid];
            #pragma unroll
            for (int v = 0; v < 32; ++v) g += qs[v] * lWhT[v * 128 + tid];
            gsv[tid] = g;
        }
        __syncthreads();
        if (tid < 32) {
            float ci = sigf(gsv[32 + tid]) * cs2[tid] + sigf(gsv[tid]) * tanhf(gsv[64 + tid]);
            cs2[tid] = ci;
            qs[tid] = sigf(gsv[96 + tid]) * tanhf(ci);
        }
        __syncthreads();
        if (tid < 32) {
            float e = 0.f;
            #pragma unroll
            for (int v = 0; v < 32; ++v) e += hsh[tid * 32 + v] * qs[v];
            e = (mskk[tid] == 0.f) ? -INFINITY : e;
            float mx = e;
            for (int o = 16; o >= 1; o >>= 1) mx = fmaxf(mx, __shfl_xor(mx, o, 64));
            float a = expf(e - mx);
            float ss = a;
            for (int o = 16; o >= 1; o >>= 1) ss += __shfl_xor(ss, o, 64);
            asv[tid] = a / ss;
        }
        __syncthreads();
        if (tid < 32) {
            float rr = 0.f;
            #pragma unroll
            for (int nn = 0; nn < 32; ++nn) rr += asv[nn] * hsh[nn * 32 + tid] * mskk[nn];
            qstar[tid] = qs[tid];
            qstar[32 + tid] = rr;
        }
        __syncthreads();
    }
    if (tid < 64) {
        float v = qstar[tid] * Wf[tid];
        for (int o = 32; o >= 1; o >>= 1) v += __shfl_xor(v, o, 64);
        if (tid == 0) out[b] = v + bf[0];
    }
}

extern "C" void kernel_launch(void* const* d_in, const int* in_sizes, int n_in,
                              void* d_out, int out_size, void* d_ws, size_t ws_size,
                              hipStream_t stream) {
    const float* x    = (const float*)d_in[0];
    const float* edge = (const float*)d_in[1];
    const float* adj  = (const float*)d_in[2];
    const float* W_emb= (const float*)d_in[3];
    const float* b_emb= (const float*)d_in[4];
    const float* W1   = (const float*)d_in[5];
    const float* b1   = (const float*)d_in[6];
    const float* W2   = (const float*)d_in[7];
    const float* b2   = (const float*)d_in[8];
    const float* gWi  = (const float*)d_in[9];
    const float* gWh  = (const float*)d_in[10];
    const float* gbi  = (const float*)d_in[11];
    const float* gbh  = (const float*)d_in[12];
    const float* lWi  = (const float*)d_in[13];
    const float* lWh  = (const float*)d_in[14];
    const float* lbi  = (const float*)d_in[15];
    const float* lbh  = (const float*)d_in[16];
    const float* Wf   = (const float*)d_in[17];
    const float* bf   = (const float*)d_in[18];
    float* out = (float*)d_out;

    __hip_bfloat16* taT2  = (__hip_bfloat16*)d_ws;      // 8388608 bf16
    __hip_bfloat16* W2FTB = taT2 + 8388608;             // 131072 bf16
    float* hA   = (float*)(W2FTB + 131072);             // 65536 f32
    float* hB   = hA + 65536;                           // 65536 f32
    float* mskp = hB + 65536;                           // 2048 f32
    float* partial = mskp + 2048;                       // 262144 f32
    float* gWiT = partial + 262144;                     // 3072
    float* gWhT = gWiT + 3072;                          // 3072
    float* b2T  = gWhT + 3072;                          // 1024
    float* lWiT = b2T + 1024;                           // 8192
    float* lWhT = lWiT + 8192;                          // 4096

    k_prep<<<2048, 256, 0, stream>>>(edge, adj, W1, b1, x, W_emb, b_emb, W2,
                                     gWi, gWh, b2, lWi, lWh,
                                     taT2, W2FTB, hA, mskp,
                                     gWiT, gWhT, b2T, lWiT, lWhT);
    float* hcur = hA; float* hnxt = hB;
    for (int l = 0; l < 3; ++l) {
        k_msg<<<256, 256, 0, stream>>>(taT2, W2FTB, hcur, partial);
        k_gru<<<256, 256, 0, stream>>>(partial, hcur, adj, mskp, b2T,
                                       gWiT, gWhT, gbi, gbh, hnxt);
        float* tf = hcur; hcur = hnxt; hnxt = tf;
    }
    k_s2s<<<64, 128, 0, stream>>>(hcur, mskp, lWiT, lWhT, lbi, lbh, Wf, bf, out);
}